// Round 1
// baseline (269.908 us; speedup 1.0000x reference)
//
#include <hip/hip_runtime.h>
#include <hip/hip_bf16.h>

typedef __bf16 bf16_t;
typedef __bf16 bf16x4 __attribute__((ext_vector_type(4)));
typedef __bf16 bf16x8 __attribute__((ext_vector_type(8)));
typedef float f32x4 __attribute__((ext_vector_type(4)));

// ---------------- prep: fold proj_mat into w_qkv -> WeffT [1536][512] (B^T layout) ----
// n in [0,512):   q-effective col n=h*64+f : WeffT[n][i] = sum_d w_qkv[i][h*64+d]*proj[h][d][f]
// n in [512,1024): k-effective (w_qkv cols 512+)
// n in [1024,1536): v passthrough WeffT[n][i] = w_qkv[i][n]
__global__ __launch_bounds__(256) void prep_weights(const float* __restrict__ w_qkv,
                                                    const float* __restrict__ proj,
                                                    bf16_t* __restrict__ WeffT) {
  const int n = blockIdx.x;
  const int t = threadIdx.x;
  if (n < 1024) {
    const int half = n >> 9, nn = n & 511;
    const int h = nn >> 6, f = nn & 63;
    const int base = half * 512 + h * 64;
    __shared__ float pcol[64];
    if (t < 64) pcol[t] = proj[((size_t)(h * 64 + t)) * 64 + f];
    __syncthreads();
    for (int i = t; i < 512; i += 256) {
      const float* wrow = w_qkv + (size_t)i * 1536 + base;
      float s = 0.f;
      #pragma unroll
      for (int d = 0; d < 64; ++d) s += wrow[d] * pcol[d];
      WeffT[(size_t)n * 512 + i] = (bf16_t)s;
    }
  } else {
    for (int i = t; i < 512; i += 256)
      WeffT[(size_t)n * 512 + i] = (bf16_t)w_qkv[(size_t)i * 1536 + n];
  }
}

// ---------------- cast x (f32) -> bf16 ----------------
__global__ __launch_bounds__(256) void cast_x(const f32x4* __restrict__ x,
                                              bf16x4* __restrict__ xb, int n4) {
  int i = blockIdx.x * 256 + threadIdx.x;
  if (i < n4) {
    f32x4 v = x[i];
    bf16x4 o;
    #pragma unroll
    for (int j = 0; j < 4; ++j) o[j] = (bf16_t)v[j];
    xb[i] = o;
  }
}

// ---------------- MFMA GEMM, C = A[M][512] * Bt[N][512]^T ----------------
// MODE 0: epilogue phi on cols<1024, bf16 out (row stride Ncols=1536)
// MODE 1: epilogue +bias, f32 out (batched via blockIdx.z)
template <int MODE>
__global__ __launch_bounds__(256) void gemm_bt(const bf16_t* __restrict__ A,
                                               const bf16_t* __restrict__ Bt,
                                               bf16_t* __restrict__ Cb,
                                               float* __restrict__ Cf,
                                               const float* __restrict__ bias, int Ncols,
                                               size_t sA, size_t sB, size_t sC) {
  constexpr int K = 512;
  __shared__ alignas(16) bf16_t As[128][32];
  __shared__ alignas(16) bf16_t Bs[128][32];
  const int t = threadIdx.x;
  const int z = blockIdx.z;
  const bf16_t* Ap = A + (size_t)z * sA;
  const bf16_t* Bp = Bt + (size_t)z * sB;
  const int w = t >> 6, l = t & 63;
  const int wr = w >> 1, wc = w & 1;
  const int lrow = l & 15, lkb = l >> 4;
  const size_t am0 = (size_t)blockIdx.x * 128;
  const size_t bn0 = (size_t)blockIdx.y * 128;

  f32x4 acc[4][4];
  #pragma unroll
  for (int m = 0; m < 4; ++m)
    #pragma unroll
    for (int n = 0; n < 4; ++n) acc[m][n] = f32x4{0.f, 0.f, 0.f, 0.f};

  const int r0 = t >> 2, c8 = (t & 3) * 8;
  for (int kt = 0; kt < K; kt += 32) {
    *(bf16x8*)&As[r0][c8]      = *(const bf16x8*)&Ap[(am0 + r0) * K + kt + c8];
    *(bf16x8*)&As[r0 + 64][c8] = *(const bf16x8*)&Ap[(am0 + r0 + 64) * K + kt + c8];
    *(bf16x8*)&Bs[r0][c8]      = *(const bf16x8*)&Bp[(bn0 + r0) * K + kt + c8];
    *(bf16x8*)&Bs[r0 + 64][c8] = *(const bf16x8*)&Bp[(bn0 + r0 + 64) * K + kt + c8];
    __syncthreads();
    bf16x8 af[4], bfr[4];
    #pragma unroll
    for (int m = 0; m < 4; ++m) af[m] = *(const bf16x8*)&As[wr * 64 + m * 16 + lrow][lkb * 8];
    #pragma unroll
    for (int n = 0; n < 4; ++n) bfr[n] = *(const bf16x8*)&Bs[wc * 64 + n * 16 + lrow][lkb * 8];
    #pragma unroll
    for (int m = 0; m < 4; ++m)
      #pragma unroll
      for (int n = 0; n < 4; ++n)
        acc[m][n] = __builtin_amdgcn_mfma_f32_16x16x32_bf16(af[m], bfr[n], acc[m][n], 0, 0, 0);
    __syncthreads();
  }

  #pragma unroll
  for (int m = 0; m < 4; ++m) {
    #pragma unroll
    for (int n = 0; n < 4; ++n) {
      #pragma unroll
      for (int j = 0; j < 4; ++j) {
        const size_t row = am0 + wr * 64 + m * 16 + lkb * 4 + j;
        const int col = (int)bn0 + wc * 64 + n * 16 + lrow;
        float v = acc[m][n][j];
        if (MODE == 0) {
          if (col < 1024) v = v > 0.f ? v + 1.f : __expf(v);  // elu(v)+1
          Cb[row * (size_t)Ncols + col] = (bf16_t)v;
        } else {
          (Cf + (size_t)z * sC)[row * (size_t)Ncols + col] = v + bias[col];
        }
      }
    }
  }
}

// ---------------- kv[b,h,f,d] = sum_n kphi*v ; ksum[b,h,f] = sum_n kphi ----------------
__global__ __launch_bounds__(256) void kv_kernel(const bf16_t* __restrict__ phiV,
                                                 float* __restrict__ kv,
                                                 float* __restrict__ ksum) {
  const int bh = blockIdx.x, b = bh >> 3, h = bh & 7;
  const int n0 = blockIdx.y * 512;
  const int t = threadIdx.x;
  __shared__ alignas(16) bf16_t kl[32][64];
  __shared__ alignas(16) bf16_t vl[32][64];
  const int fq = t >> 4, dq = t & 15;
  float acc[4][4] = {};
  float ks[4] = {};
  const int r = t >> 3, c8 = (t & 7) * 8;
  for (int st = 0; st < 16; ++st) {
    const bf16_t* src = phiV + ((size_t)b * 4096 + n0 + st * 32 + r) * 1536 + h * 64;
    *(bf16x8*)&kl[r][c8] = *(const bf16x8*)&src[512 + c8];
    *(bf16x8*)&vl[r][c8] = *(const bf16x8*)&src[1024 + c8];
    __syncthreads();
    #pragma unroll 8
    for (int nn = 0; nn < 32; ++nn) {
      bf16x4 k4 = *(const bf16x4*)&kl[nn][fq * 4];
      bf16x4 v4 = *(const bf16x4*)&vl[nn][dq * 4];
      float kf[4], vd[4];
      #pragma unroll
      for (int i2 = 0; i2 < 4; ++i2) { kf[i2] = (float)k4[i2]; vd[i2] = (float)v4[i2]; }
      #pragma unroll
      for (int i2 = 0; i2 < 4; ++i2) {
        ks[i2] += kf[i2];
        #pragma unroll
        for (int j = 0; j < 4; ++j) acc[i2][j] += kf[i2] * vd[j];
      }
    }
    __syncthreads();
  }
  float* kvp = kv + (size_t)bh * 4096;
  #pragma unroll
  for (int i2 = 0; i2 < 4; ++i2)
    #pragma unroll
    for (int j = 0; j < 4; ++j)
      atomicAdd(&kvp[(fq * 4 + i2) * 64 + dq * 4 + j], acc[i2][j]);
  if (dq == 0) {
    float* ksp = ksum + (size_t)bh * 64;
    #pragma unroll
    for (int i2 = 0; i2 < 4; ++i2) atomicAdd(&ksp[fq * 4 + i2], ks[i2]);
  }
}

// ---------------- W2T[b][j][h*64+f] = sum_d kv[b,h,f,d] * w_proj[h*64+d][j] ----------------
__global__ __launch_bounds__(256) void w2_kernel(const float* __restrict__ kv,
                                                 const float* __restrict__ w_proj,
                                                 bf16_t* __restrict__ W2T) {
  const int bh = blockIdx.x, b = bh >> 3, h = bh & 7;
  const int j0 = blockIdx.y * 64;
  const int t = threadIdx.x;
  __shared__ float kvs[64][64];
  __shared__ float wps[64][64];
  const float* kvp = kv + (size_t)bh * 4096;
  #pragma unroll
  for (int i = 0; i < 16; ++i) ((float*)kvs)[t + 256 * i] = kvp[t + 256 * i];
  {
    const int d = t >> 2, c16 = (t & 3) * 16;
    const float* src = w_proj + (size_t)(h * 64 + d) * 512 + j0 + c16;
    #pragma unroll
    for (int j = 0; j < 16; ++j) wps[d][c16 + j] = src[j];
  }
  __syncthreads();
  const int fq = t >> 4, jq = t & 15;
  float acc[4][4] = {};
  for (int d = 0; d < 64; ++d) {
    float kf[4], wj[4];
    #pragma unroll
    for (int i = 0; i < 4; ++i) kf[i] = kvs[fq * 4 + i][d];
    #pragma unroll
    for (int i = 0; i < 4; ++i) wj[i] = wps[d][jq * 4 + i];
    #pragma unroll
    for (int i = 0; i < 4; ++i)
      #pragma unroll
      for (int j = 0; j < 4; ++j) acc[i][j] += kf[i] * wj[j];
  }
  #pragma unroll
  for (int j = 0; j < 4; ++j)
    #pragma unroll
    for (int i = 0; i < 4; ++i)
      W2T[((size_t)b * 512 + j0 + jq * 4 + j) * 512 + h * 64 + fq * 4 + i] = (bf16_t)acc[i][j];
}

// ---------------- zq[row][h*64+f] = qphi * (1 / sum_f qphi*ksum) ----------------
__global__ __launch_bounds__(256) void zq_kernel(const bf16_t* __restrict__ phiV,
                                                 const float* __restrict__ ksum,
                                                 bf16_t* __restrict__ zq) {
  const int row = blockIdx.x * 4 + (threadIdx.x >> 6);
  const int l = threadIdx.x & 63;
  const int b = row >> 12;
  const int h = l >> 3, f8 = (l & 7) * 8;
  const bf16_t* src = phiV + (size_t)row * 1536 + h * 64 + f8;
  bf16x8 v = *(const bf16x8*)src;
  const float* ks = ksum + ((size_t)b * 8 + h) * 64 + f8;
  float part = 0.f;
  float vf[8];
  #pragma unroll
  for (int j = 0; j < 8; ++j) { vf[j] = (float)v[j]; part += vf[j] * ks[j]; }
  part += __shfl_xor(part, 1);
  part += __shfl_xor(part, 2);
  part += __shfl_xor(part, 4);
  const float z = 1.f / part;
  bf16x8 o;
  #pragma unroll
  for (int j = 0; j < 8; ++j) o[j] = (bf16_t)(vf[j] * z);
  *(bf16x8*)(zq + (size_t)row * 512 + h * 64 + f8) = o;
}

extern "C" void kernel_launch(void* const* d_in, const int* in_sizes, int n_in,
                              void* d_out, int out_size, void* d_ws, size_t ws_size,
                              hipStream_t stream) {
  const float* x      = (const float*)d_in[0];
  const float* w_qkv  = (const float*)d_in[1];
  const float* proj   = (const float*)d_in[2];
  const float* w_proj = (const float*)d_in[3];
  const float* b_proj = (const float*)d_in[4];
  float* out = (float*)d_out;
  char* ws = (char*)d_ws;

  // workspace layout (bytes)
  bf16_t* x_bf  = (bf16_t*)(ws + 0);          // 32768*512*2   = 33,554,432
  bf16_t* WeffT = (bf16_t*)(ws + 33554432);   // 1536*512*2    =  1,572,864
  bf16_t* phiV  = (bf16_t*)(ws + 35127296);   // 32768*1536*2  = 100,663,296
  float*  kv    = (float*)(ws + 135790592);   // 8*8*64*64*4   =  1,048,576
  float*  ksum  = (float*)(ws + 136839168);   // 8*8*64*4      =     16,384
  bf16_t* W2T   = (bf16_t*)(ws + 136855552);  // 8*512*512*2   =  4,194,304
  bf16_t* zq    = (bf16_t*)(ws + 141049856);  // 32768*512*2   = 33,554,432
                                              // total ~174.6 MB

  prep_weights<<<1536, 256, 0, stream>>>(w_qkv, proj, WeffT);
  cast_x<<<16384, 256, 0, stream>>>((const f32x4*)x, (bf16x4*)x_bf, 4194304);
  gemm_bt<0><<<dim3(256, 12, 1), 256, 0, stream>>>(x_bf, WeffT, phiV, nullptr, nullptr, 1536,
                                                   0, 0, 0);
  hipMemsetAsync(kv, 0, 1048576 + 16384, stream);
  kv_kernel<<<dim3(64, 8), 256, 0, stream>>>(phiV, kv, ksum);
  w2_kernel<<<dim3(64, 8), 256, 0, stream>>>(kv, w_proj, W2T);
  zq_kernel<<<8192, 256, 0, stream>>>(phiV, ksum, zq);
  gemm_bt<1><<<dim3(32, 4, 8), 256, 0, stream>>>(zq, W2T, nullptr, out, b_proj, 512,
                                                 (size_t)4096 * 512, (size_t)512 * 512,
                                                 (size_t)4096 * 512);
}

// Round 2
// 239.017 us; speedup vs baseline: 1.1292x; 1.1292x over previous
//
#include <hip/hip_runtime.h>
#include <hip/hip_bf16.h>

typedef __bf16 bf16_t;
typedef __bf16 bf16x4 __attribute__((ext_vector_type(4)));
typedef __bf16 bf16x8 __attribute__((ext_vector_type(8)));
typedef float f32x4 __attribute__((ext_vector_type(4)));

__device__ __forceinline__ void gload16(const void* g, void* l) {
  __builtin_amdgcn_global_load_lds((const __attribute__((address_space(1))) void*)g,
                                   (__attribute__((address_space(3))) void*)l, 16, 0, 0);
}

// ---------------- prep: fold proj into w_qkv (q,k halves) ----------------
// WeffT[n=half*512+h*64+f][i] = sum_d w_qkv[i][half*512+h*64+d] * proj[h][d][f]
__global__ __launch_bounds__(256) void prep_qk(const float* __restrict__ w_qkv,
                                               const float* __restrict__ proj,
                                               bf16_t* __restrict__ WeffT) {
  const int half = blockIdx.x >> 3, h = blockIdx.x & 7;
  const int i0 = blockIdx.y * 64;
  __shared__ float P[64 * 64];   // [d][f] == proj[h] layout
  __shared__ float Wt[64][65];   // [ii][d], padded
  const int t = threadIdx.x;
  #pragma unroll
  for (int r = 0; r < 16; ++r) P[t + 256 * r] = proj[(size_t)h * 4096 + t + 256 * r];
  #pragma unroll
  for (int r = 0; r < 16; ++r) {
    const int idx = t + 256 * r;  // ii = idx>>6, d = idx&63
    Wt[idx >> 6][idx & 63] =
        w_qkv[(size_t)(i0 + (idx >> 6)) * 1536 + half * 512 + h * 64 + (idx & 63)];
  }
  __syncthreads();
  const int i = t & 63, fg = t >> 6;
  for (int f = fg; f < 64; f += 4) {
    float s = 0.f;
    #pragma unroll
    for (int d = 0; d < 64; ++d) s += Wt[i][d] * P[d * 64 + f];
    WeffT[(size_t)(half * 512 + h * 64 + f) * 512 + i0 + i] = (bf16_t)s;
  }
}

// ---------------- prep: v passthrough transpose ----------------
// WeffT[1024+n][i] = w_qkv[i][1024+n]
__global__ __launch_bounds__(256) void prep_v(const float* __restrict__ w_qkv,
                                              bf16_t* __restrict__ WeffT) {
  __shared__ bf16_t tile[32][33];
  const int i0 = blockIdx.x * 32, n0 = blockIdx.y * 32;
  const int tn = threadIdx.x & 31, ti = threadIdx.x >> 5;
  #pragma unroll
  for (int p = 0; p < 4; ++p) {
    const int i = ti + p * 8;
    tile[i][tn] = (bf16_t)w_qkv[(size_t)(i0 + i) * 1536 + 1024 + n0 + tn];
  }
  __syncthreads();
  #pragma unroll
  for (int p = 0; p < 4; ++p) {
    const int n = ti + p * 8;
    WeffT[(size_t)(1024 + n0 + n) * 512 + i0 + tn] = tile[tn][n];
  }
}

// ---------------- cast x (f32) -> bf16 ----------------
__global__ __launch_bounds__(256) void cast_x(const f32x4* __restrict__ x,
                                              bf16x4* __restrict__ xb, int n4) {
  int i = blockIdx.x * 256 + threadIdx.x;
  if (i < n4) {
    f32x4 v = x[i];
    bf16x4 o;
    #pragma unroll
    for (int j = 0; j < 4; ++j) o[j] = (bf16_t)v[j];
    xb[i] = o;
  }
}

// ---------------- MFMA GEMM, C = A[M][512] * Bt[N][512]^T ----------------
// m97 structure: 128x128 tile, BK=64, global_load_lds width=16,
// XOR swizzle (slot ^= row&7) on both the global source and the ds_read.
// MODE 0: epilogue phi on cols<1024, bf16 out. MODE 1: +bias, f32 out, batched.
template <int MODE>
__global__ __launch_bounds__(256) void gemm_bt(const bf16_t* __restrict__ A,
                                               const bf16_t* __restrict__ Bt,
                                               bf16_t* __restrict__ Cb,
                                               float* __restrict__ Cf,
                                               const float* __restrict__ bias, int Ncols,
                                               size_t sA, size_t sB, size_t sC) {
  constexpr int K = 512;
  constexpr int BK = 64;
  __shared__ alignas(16) bf16_t As[128 * BK];  // swizzled storage, 16 KB
  __shared__ alignas(16) bf16_t Bs[128 * BK];
  const int t = threadIdx.x;
  const int z = blockIdx.z;
  const bf16_t* Ap = A + (size_t)z * sA;
  const bf16_t* Bp = Bt + (size_t)z * sB;
  const int w = t >> 6, l = t & 63;
  const int wr = w >> 1, wc = w & 1;
  const int lrow = l & 15, lkb = l >> 4;
  const size_t am0 = (size_t)blockIdx.x * 128;
  const size_t bn0 = (size_t)blockIdx.y * 128;

  // staging geometry: chunk q = c*4+w covers LDS bytes [q*1024,(q+1)*1024)
  // = rows [q*8, q*8+8) of the [128][64] tile (128 B/row).
  // lane l -> row = q*8 + (l>>3), slot = l&7 (16B slots).
  // source column slot is pre-swizzled: src_slot = slot ^ (row&7), row&7 == l>>3.
  const int st_r = l >> 3;                    // row-within-chunk and row&7
  const int st_c = ((l & 7) ^ st_r) * 8;      // pre-swizzled source col (bf16 units)
  size_t a_src[4], b_src[4];
  #pragma unroll
  for (int c = 0; c < 4; ++c) {
    const int q = c * 4 + w;
    a_src[c] = (am0 + q * 8 + st_r) * (size_t)K + st_c;
    b_src[c] = (bn0 + q * 8 + st_r) * (size_t)K + st_c;
  }

  f32x4 acc[4][4];
  #pragma unroll
  for (int m = 0; m < 4; ++m)
    #pragma unroll
    for (int n = 0; n < 4; ++n) acc[m][n] = f32x4{0.f, 0.f, 0.f, 0.f};

  // ds_read addresses (swizzled): row r, k-slot kb -> byte r*128 + ((kb^(r&7))<<4)
  const char* AsB = (const char*)As;
  const char* BsB = (const char*)Bs;

  for (int kt = 0; kt < K; kt += BK) {
    #pragma unroll
    for (int c = 0; c < 4; ++c) {
      const int q = c * 4 + w;
      gload16(Ap + a_src[c] + kt, (char*)As + q * 1024);
      gload16(Bp + b_src[c] + kt, (char*)Bs + q * 1024);
    }
    __syncthreads();
    bf16x8 af[4][2], bfr[4][2];
    #pragma unroll
    for (int m = 0; m < 4; ++m) {
      const int r = wr * 64 + m * 16 + lrow;
      #pragma unroll
      for (int kk = 0; kk < 2; ++kk) {
        const int kb = lkb + kk * 4;
        af[m][kk] = *(const bf16x8*)(AsB + r * 128 + (((kb ^ (r & 7)) & 7) << 4));
      }
    }
    #pragma unroll
    for (int n = 0; n < 4; ++n) {
      const int r = wc * 64 + n * 16 + lrow;
      #pragma unroll
      for (int kk = 0; kk < 2; ++kk) {
        const int kb = lkb + kk * 4;
        bfr[n][kk] = *(const bf16x8*)(BsB + r * 128 + (((kb ^ (r & 7)) & 7) << 4));
      }
    }
    #pragma unroll
    for (int m = 0; m < 4; ++m)
      #pragma unroll
      for (int n = 0; n < 4; ++n) {
        acc[m][n] = __builtin_amdgcn_mfma_f32_16x16x32_bf16(af[m][0], bfr[n][0], acc[m][n], 0, 0, 0);
        acc[m][n] = __builtin_amdgcn_mfma_f32_16x16x32_bf16(af[m][1], bfr[n][1], acc[m][n], 0, 0, 0);
      }
    __syncthreads();
  }

  #pragma unroll
  for (int m = 0; m < 4; ++m) {
    #pragma unroll
    for (int n = 0; n < 4; ++n) {
      #pragma unroll
      for (int j = 0; j < 4; ++j) {
        const size_t row = am0 + wr * 64 + m * 16 + lkb * 4 + j;
        const int col = (int)bn0 + wc * 64 + n * 16 + lrow;
        float v = acc[m][n][j];
        if (MODE == 0) {
          if (col < 1024) v = v > 0.f ? v + 1.f : __expf(v);  // elu(v)+1
          Cb[row * (size_t)Ncols + col] = (bf16_t)v;
        } else {
          (Cf + (size_t)z * sC)[row * (size_t)Ncols + col] = v + bias[col];
        }
      }
    }
  }
}

// ---------------- kv[b,h,f,d] = sum_n kphi*v ; ksum[b,h,f] = sum_n kphi ----------------
__global__ __launch_bounds__(256) void kv_kernel(const bf16_t* __restrict__ phiV,
                                                 float* __restrict__ kv,
                                                 float* __restrict__ ksum) {
  const int bh = blockIdx.x, b = bh >> 3, h = bh & 7;
  const int n0 = blockIdx.y * 512;
  const int t = threadIdx.x;
  __shared__ alignas(16) bf16_t kl[32][64];
  __shared__ alignas(16) bf16_t vl[32][64];
  const int fq = t >> 4, dq = t & 15;
  float acc[4][4] = {};
  float ks[4] = {};
  const int r = t >> 3, c8 = (t & 7) * 8;
  for (int st = 0; st < 16; ++st) {
    const bf16_t* src = phiV + ((size_t)b * 4096 + n0 + st * 32 + r) * 1536 + h * 64;
    *(bf16x8*)&kl[r][c8] = *(const bf16x8*)&src[512 + c8];
    *(bf16x8*)&vl[r][c8] = *(const bf16x8*)&src[1024 + c8];
    __syncthreads();
    #pragma unroll 8
    for (int nn = 0; nn < 32; ++nn) {
      bf16x4 k4 = *(const bf16x4*)&kl[nn][fq * 4];
      bf16x4 v4 = *(const bf16x4*)&vl[nn][dq * 4];
      float kf[4], vd[4];
      #pragma unroll
      for (int i2 = 0; i2 < 4; ++i2) { kf[i2] = (float)k4[i2]; vd[i2] = (float)v4[i2]; }
      #pragma unroll
      for (int i2 = 0; i2 < 4; ++i2) {
        ks[i2] += kf[i2];
        #pragma unroll
        for (int j = 0; j < 4; ++j) acc[i2][j] += kf[i2] * vd[j];
      }
    }
    __syncthreads();
  }
  float* kvp = kv + (size_t)bh * 4096;
  #pragma unroll
  for (int i2 = 0; i2 < 4; ++i2)
    #pragma unroll
    for (int j = 0; j < 4; ++j)
      atomicAdd(&kvp[(fq * 4 + i2) * 64 + dq * 4 + j], acc[i2][j]);
  if (dq == 0) {
    float* ksp = ksum + (size_t)bh * 64;
    #pragma unroll
    for (int i2 = 0; i2 < 4; ++i2) atomicAdd(&ksp[fq * 4 + i2], ks[i2]);
  }
}

// ---------------- W2T[b][j][h*64+f] = sum_d kv[b,h,f,d] * w_proj[h*64+d][j] ----------------
__global__ __launch_bounds__(256) void w2_kernel(const float* __restrict__ kv,
                                                 const float* __restrict__ w_proj,
                                                 bf16_t* __restrict__ W2T) {
  const int bh = blockIdx.x, b = bh >> 3, h = bh & 7;
  const int j0 = blockIdx.y * 64;
  const int t = threadIdx.x;
  __shared__ float kvs[64][64];
  __shared__ float wps[64][64];
  const float* kvp = kv + (size_t)bh * 4096;
  #pragma unroll
  for (int i = 0; i < 16; ++i) ((float*)kvs)[t + 256 * i] = kvp[t + 256 * i];
  {
    const int d = t >> 2, c16 = (t & 3) * 16;
    const float* src = w_proj + (size_t)(h * 64 + d) * 512 + j0 + c16;
    #pragma unroll
    for (int j = 0; j < 16; ++j) wps[d][c16 + j] = src[j];
  }
  __syncthreads();
  const int fq = t >> 4, jq = t & 15;
  float acc[4][4] = {};
  for (int d = 0; d < 64; ++d) {
    float kf[4], wj[4];
    #pragma unroll
    for (int i = 0; i < 4; ++i) kf[i] = kvs[fq * 4 + i][d];
    #pragma unroll
    for (int i = 0; i < 4; ++i) wj[i] = wps[d][jq * 4 + i];
    #pragma unroll
    for (int i = 0; i < 4; ++i)
      #pragma unroll
      for (int j = 0; j < 4; ++j) acc[i][j] += kf[i] * wj[j];
  }
  #pragma unroll
  for (int j = 0; j < 4; ++j)
    #pragma unroll
    for (int i = 0; i < 4; ++i)
      W2T[((size_t)b * 512 + j0 + jq * 4 + j) * 512 + h * 64 + fq * 4 + i] = (bf16_t)acc[i][j];
}

// ---------------- zq[row][h*64+f] = qphi * (1 / sum_f qphi*ksum) ----------------
__global__ __launch_bounds__(256) void zq_kernel(const bf16_t* __restrict__ phiV,
                                                 const float* __restrict__ ksum,
                                                 bf16_t* __restrict__ zq) {
  const int row = blockIdx.x * 4 + (threadIdx.x >> 6);
  const int l = threadIdx.x & 63;
  const int b = row >> 12;
  const int h = l >> 3, f8 = (l & 7) * 8;
  const bf16_t* src = phiV + (size_t)row * 1536 + h * 64 + f8;
  bf16x8 v = *(const bf16x8*)src;
  const float* ks = ksum + ((size_t)b * 8 + h) * 64 + f8;
  float part = 0.f;
  float vf[8];
  #pragma unroll
  for (int j = 0; j < 8; ++j) { vf[j] = (float)v[j]; part += vf[j] * ks[j]; }
  part += __shfl_xor(part, 1);
  part += __shfl_xor(part, 2);
  part += __shfl_xor(part, 4);
  const float z = 1.f / part;
  bf16x8 o;
  #pragma unroll
  for (int j = 0; j < 8; ++j) o[j] = (bf16_t)(vf[j] * z);
  *(bf16x8*)(zq + (size_t)row * 512 + h * 64 + f8) = o;
}

extern "C" void kernel_launch(void* const* d_in, const int* in_sizes, int n_in,
                              void* d_out, int out_size, void* d_ws, size_t ws_size,
                              hipStream_t stream) {
  const float* x      = (const float*)d_in[0];
  const float* w_qkv  = (const float*)d_in[1];
  const float* proj   = (const float*)d_in[2];
  const float* w_proj = (const float*)d_in[3];
  const float* b_proj = (const float*)d_in[4];
  float* out = (float*)d_out;
  char* ws = (char*)d_ws;

  // workspace layout (bytes)
  bf16_t* x_bf  = (bf16_t*)(ws + 0);          // 32768*512*2   = 33,554,432
  bf16_t* WeffT = (bf16_t*)(ws + 33554432);   // 1536*512*2    =  1,572,864
  bf16_t* phiV  = (bf16_t*)(ws + 35127296);   // 32768*1536*2  = 100,663,296
  float*  kv    = (float*)(ws + 135790592);   // 8*8*64*64*4   =  1,048,576
  float*  ksum  = (float*)(ws + 136839168);   // 8*8*64*4      =     16,384
  bf16_t* W2T   = (bf16_t*)(ws + 136855552);  // 8*512*512*2   =  4,194,304
  bf16_t* zq    = (bf16_t*)(ws + 141049856);  // 32768*512*2   = 33,554,432

  prep_qk<<<dim3(16, 8), 256, 0, stream>>>(w_qkv, proj, WeffT);
  prep_v<<<dim3(16, 16), 256, 0, stream>>>(w_qkv, WeffT);
  cast_x<<<16384, 256, 0, stream>>>((const f32x4*)x, (bf16x4*)x_bf, 4194304);
  gemm_bt<0><<<dim3(256, 12, 1), 256, 0, stream>>>(x_bf, WeffT, phiV, nullptr, nullptr, 1536,
                                                   0, 0, 0);
  hipMemsetAsync(kv, 0, 1048576 + 16384, stream);
  kv_kernel<<<dim3(64, 8), 256, 0, stream>>>(phiV, kv, ksum);
  w2_kernel<<<dim3(64, 8), 256, 0, stream>>>(kv, w_proj, W2T);
  zq_kernel<<<8192, 256, 0, stream>>>(phiV, ksum, zq);
  gemm_bt<1><<<dim3(32, 4, 8), 256, 0, stream>>>(zq, W2T, nullptr, out, b_proj, 512,
                                                 (size_t)4096 * 512, (size_t)512 * 512,
                                                 (size_t)4096 * 512);
}

// Round 3
// 200.152 us; speedup vs baseline: 1.3485x; 1.1942x over previous
//
#include <hip/hip_runtime.h>
#include <hip/hip_bf16.h>

typedef __bf16 bf16_t;
typedef __bf16 bf16x4 __attribute__((ext_vector_type(4)));
typedef __bf16 bf16x8 __attribute__((ext_vector_type(8)));
typedef float f32x4 __attribute__((ext_vector_type(4)));

__device__ __forceinline__ void gload16(const void* g, void* l) {
  __builtin_amdgcn_global_load_lds((const __attribute__((address_space(1))) void*)g,
                                   (__attribute__((address_space(3))) void*)l, 16, 0, 0);
}

// ---------------- prep: fold proj into w_qkv (q,k halves) ----------------
__global__ __launch_bounds__(256) void prep_qk(const float* __restrict__ w_qkv,
                                               const float* __restrict__ proj,
                                               bf16_t* __restrict__ WeffT) {
  const int half = blockIdx.x >> 3, h = blockIdx.x & 7;
  const int i0 = blockIdx.y * 64;
  __shared__ float P[64 * 64];   // [d][f] == proj[h] layout
  __shared__ float Wt[64][65];   // [ii][d], padded
  const int t = threadIdx.x;
  #pragma unroll
  for (int r = 0; r < 16; ++r) P[t + 256 * r] = proj[(size_t)h * 4096 + t + 256 * r];
  #pragma unroll
  for (int r = 0; r < 16; ++r) {
    const int idx = t + 256 * r;
    Wt[idx >> 6][idx & 63] =
        w_qkv[(size_t)(i0 + (idx >> 6)) * 1536 + half * 512 + h * 64 + (idx & 63)];
  }
  __syncthreads();
  const int i = t & 63, fg = t >> 6;
  for (int f = fg; f < 64; f += 4) {
    float s = 0.f;
    #pragma unroll
    for (int d = 0; d < 64; ++d) s += Wt[i][d] * P[d * 64 + f];
    WeffT[(size_t)(half * 512 + h * 64 + f) * 512 + i0 + i] = (bf16_t)s;
  }
}

// ---------------- prep: v passthrough transpose ----------------
__global__ __launch_bounds__(256) void prep_v(const float* __restrict__ w_qkv,
                                              bf16_t* __restrict__ WeffT) {
  __shared__ bf16_t tile[32][33];
  const int i0 = blockIdx.x * 32, n0 = blockIdx.y * 32;
  const int tn = threadIdx.x & 31, ti = threadIdx.x >> 5;
  #pragma unroll
  for (int p = 0; p < 4; ++p) {
    const int i = ti + p * 8;
    tile[i][tn] = (bf16_t)w_qkv[(size_t)(i0 + i) * 1536 + 1024 + n0 + tn];
  }
  __syncthreads();
  #pragma unroll
  for (int p = 0; p < 4; ++p) {
    const int n = ti + p * 8;
    WeffT[(size_t)(1024 + n0 + n) * 512 + i0 + tn] = tile[tn][n];
  }
}

// ---------------- cast x (f32) -> bf16 ----------------
__global__ __launch_bounds__(256) void cast_x(const f32x4* __restrict__ x,
                                              bf16x4* __restrict__ xb, int n4) {
  int i = blockIdx.x * 256 + threadIdx.x;
  if (i < n4) {
    f32x4 v = x[i];
    bf16x4 o;
    #pragma unroll
    for (int j = 0; j < 4; ++j) o[j] = (bf16_t)v[j];
    xb[i] = o;
  }
}

// ---------------- MFMA GEMM: D[pr][qr] = sum_k P[pr][k]*Q[qr][k] ----------------
// Lane holds 4 consecutive P-rows at one Q-row -> epilogue picks layout:
// MODE 0 (q):   P=WeffT[0:512], Q=x.   store q_phi[token][f] (elu+1), bf16x4
// MODE 1 (k,v): P=x, Q=WeffT[512:1536]. store kT/vT[bh*64+f][n] (elu+1 on k), bf16x4
// MODE 2 (out): P=W2T[z], Q=zq[z].     store out[token][j] + bias, f32x4
template <int MODE>
__global__ __launch_bounds__(256) void gemm_pq(const bf16_t* __restrict__ P,
                                               const bf16_t* __restrict__ Q,
                                               bf16_t* __restrict__ Cq,
                                               bf16_t* __restrict__ kT,
                                               bf16_t* __restrict__ vT,
                                               float* __restrict__ Cout,
                                               const float* __restrict__ bias,
                                               size_t sP, size_t sQ) {
  constexpr int K = 512;
  constexpr int BK = 64;
  __shared__ alignas(16) bf16_t Ps[128 * BK];
  __shared__ alignas(16) bf16_t Qs[128 * BK];
  const int t = threadIdx.x;
  const int z = blockIdx.z;
  const bf16_t* Pp = P + (size_t)z * sP;
  const bf16_t* Qp = Q + (size_t)z * sQ;
  const int w = t >> 6, l = t & 63;
  const int wr = w >> 1, wc = w & 1;
  const int lrow = l & 15, lkb = l >> 4;
  const size_t pm0 = (size_t)blockIdx.x * 128;
  const size_t qn0 = (size_t)blockIdx.y * 128;

  // staging: chunk q8 = c*4+w -> LDS rows [q8*8, q8*8+8); lane: row q8*8+(l>>3),
  // 16B slot (l&7); source slot pre-swizzled by row&7 == l>>3.
  const int st_r = l >> 3;
  const int st_c = ((l & 7) ^ st_r) * 8;
  size_t p_src[4], q_src[4];
  #pragma unroll
  for (int c = 0; c < 4; ++c) {
    const int q8 = c * 4 + w;
    p_src[c] = (pm0 + q8 * 8 + st_r) * (size_t)K + st_c;
    q_src[c] = (qn0 + q8 * 8 + st_r) * (size_t)K + st_c;
  }

  f32x4 acc[4][4];
  #pragma unroll
  for (int m = 0; m < 4; ++m)
    #pragma unroll
    for (int n = 0; n < 4; ++n) acc[m][n] = f32x4{0.f, 0.f, 0.f, 0.f};

  const char* PsB = (const char*)Ps;
  const char* QsB = (const char*)Qs;

  for (int kt = 0; kt < K; kt += BK) {
    #pragma unroll
    for (int c = 0; c < 4; ++c) {
      const int q8 = c * 4 + w;
      gload16(Pp + p_src[c] + kt, (char*)Ps + q8 * 1024);
      gload16(Qp + q_src[c] + kt, (char*)Qs + q8 * 1024);
    }
    __syncthreads();
    bf16x8 pf[4][2], qf[4][2];
    #pragma unroll
    for (int m = 0; m < 4; ++m) {
      const int r = wr * 64 + m * 16 + lrow;
      #pragma unroll
      for (int kk = 0; kk < 2; ++kk) {
        const int kb = lkb + kk * 4;
        pf[m][kk] = *(const bf16x8*)(PsB + r * 128 + (((kb ^ (r & 7)) & 7) << 4));
      }
    }
    #pragma unroll
    for (int n = 0; n < 4; ++n) {
      const int r = wc * 64 + n * 16 + lrow;
      #pragma unroll
      for (int kk = 0; kk < 2; ++kk) {
        const int kb = lkb + kk * 4;
        qf[n][kk] = *(const bf16x8*)(QsB + r * 128 + (((kb ^ (r & 7)) & 7) << 4));
      }
    }
    #pragma unroll
    for (int m = 0; m < 4; ++m)
      #pragma unroll
      for (int n = 0; n < 4; ++n) {
        acc[m][n] = __builtin_amdgcn_mfma_f32_16x16x32_bf16(pf[m][0], qf[n][0], acc[m][n], 0, 0, 0);
        acc[m][n] = __builtin_amdgcn_mfma_f32_16x16x32_bf16(pf[m][1], qf[n][1], acc[m][n], 0, 0, 0);
      }
    __syncthreads();
  }

  #pragma unroll
  for (int m = 0; m < 4; ++m) {
    #pragma unroll
    for (int n = 0; n < 4; ++n) {
      const int prow0 = (int)pm0 + wr * 64 + m * 16 + lkb * 4;  // 4 consecutive P rows
      const int qrow  = (int)qn0 + wc * 64 + n * 16 + lrow;     // fixed Q row
      if (MODE == 0) {
        bf16x4 o;
        #pragma unroll
        for (int j = 0; j < 4; ++j) {
          float v = acc[m][n][j];
          o[j] = (bf16_t)(v > 0.f ? v + 1.f : __expf(v));
        }
        *(bf16x4*)&Cq[(size_t)qrow * 512 + prow0] = o;
      } else if (MODE == 1) {
        const int feat = qrow;                   // 0..1023, half uniform per block
        const int half = feat >> 9, h = (feat >> 6) & 7, f = feat & 63;
        const int b = prow0 >> 12, nn = prow0 & 4095;
        bf16x4 o;
        #pragma unroll
        for (int j = 0; j < 4; ++j) {
          float v = acc[m][n][j];
          if (half == 0) v = v > 0.f ? v + 1.f : __expf(v);
          o[j] = (bf16_t)v;
        }
        bf16_t* dst = (half ? vT : kT) + ((size_t)((b * 8 + h) * 64 + f)) * 4096 + nn;
        *(bf16x4*)dst = o;
      } else {
        f32x4 v = acc[m][n];
        #pragma unroll
        for (int j = 0; j < 4; ++j) v[j] += bias[prow0 + j];
        *(f32x4*)&Cout[((size_t)z * 4096 + qrow) * 512 + prow0] = v;
      }
    }
  }
}

// ---------------- kv[f][d] = sum_n kT[f][n]*vT[d][n]; ksum[f] = sum_n kT[f][n] ----
__global__ __launch_bounds__(256) void kv_mfma(const bf16_t* __restrict__ kT,
                                               const bf16_t* __restrict__ vT,
                                               float* __restrict__ kv,
                                               float* __restrict__ ksum) {
  const int bh = blockIdx.x;
  const int nbase = blockIdx.y * 512;
  __shared__ alignas(16) bf16_t Ks[64 * 64];
  __shared__ alignas(16) bf16_t Vs[64 * 64];
  const int t = threadIdx.x, w = t >> 6, l = t & 63;
  const int wr = w >> 1, wc = w & 1;
  const int lrow = l & 15, lkb = l >> 4;
  const int st_r = l >> 3;
  const int st_c = ((l & 7) ^ st_r) * 8;
  const bf16_t* Kp = kT + (size_t)bh * 64 * 4096;
  const bf16_t* Vp = vT + (size_t)bh * 64 * 4096;
  const char* KsB = (const char*)Ks;
  const char* VsB = (const char*)Vs;

  f32x4 acc[2][2];
  #pragma unroll
  for (int m = 0; m < 2; ++m)
    #pragma unroll
    for (int n = 0; n < 2; ++n) acc[m][n] = f32x4{0.f, 0.f, 0.f, 0.f};
  float ksf[2] = {0.f, 0.f};

  for (int st = 0; st < 8; ++st) {
    const int nb = nbase + st * 64;
    #pragma unroll
    for (int c = 0; c < 2; ++c) {
      const int q8 = w * 2 + c;
      gload16(Kp + (size_t)(q8 * 8 + st_r) * 4096 + nb + st_c, (char*)Ks + q8 * 1024);
      gload16(Vp + (size_t)(q8 * 8 + st_r) * 4096 + nb + st_c, (char*)Vs + q8 * 1024);
    }
    __syncthreads();
    bf16x8 af[2][2], bf[2][2];
    #pragma unroll
    for (int m = 0; m < 2; ++m) {
      const int r = wr * 32 + m * 16 + lrow;
      #pragma unroll
      for (int kk = 0; kk < 2; ++kk) {
        const int kb = lkb + kk * 4;
        af[m][kk] = *(const bf16x8*)(KsB + r * 128 + (((kb ^ (r & 7)) & 7) << 4));
      }
    }
    #pragma unroll
    for (int n = 0; n < 2; ++n) {
      const int r = wc * 32 + n * 16 + lrow;
      #pragma unroll
      for (int kk = 0; kk < 2; ++kk) {
        const int kb = lkb + kk * 4;
        bf[n][kk] = *(const bf16x8*)(VsB + r * 128 + (((kb ^ (r & 7)) & 7) << 4));
      }
    }
    #pragma unroll
    for (int m = 0; m < 2; ++m)
      #pragma unroll
      for (int n = 0; n < 2; ++n) {
        acc[m][n] = __builtin_amdgcn_mfma_f32_16x16x32_bf16(af[m][0], bf[n][0], acc[m][n], 0, 0, 0);
        acc[m][n] = __builtin_amdgcn_mfma_f32_16x16x32_bf16(af[m][1], bf[n][1], acc[m][n], 0, 0, 0);
      }
    if (wc == 0) {
      #pragma unroll
      for (int m = 0; m < 2; ++m)
        #pragma unroll
        for (int kk = 0; kk < 2; ++kk)
          #pragma unroll
          for (int j = 0; j < 8; ++j) ksf[m] += (float)af[m][kk][j];
    }
    __syncthreads();
  }

  float* kvp = kv + (size_t)bh * 4096;
  #pragma unroll
  for (int m = 0; m < 2; ++m)
    #pragma unroll
    for (int n = 0; n < 2; ++n)
      #pragma unroll
      for (int j = 0; j < 4; ++j)
        atomicAdd(&kvp[(wr * 32 + m * 16 + lkb * 4 + j) * 64 + wc * 32 + n * 16 + lrow],
                  acc[m][n][j]);
  if (wc == 0) {
    #pragma unroll
    for (int m = 0; m < 2; ++m) {
      float s = ksf[m];
      s += __shfl_xor(s, 16);
      s += __shfl_xor(s, 32);
      if (l < 16) atomicAdd(&ksum[(size_t)bh * 64 + wr * 32 + m * 16 + l], s);
    }
  }
}

// ---------------- W2T[b][j][h*64+f] = sum_d kv[b,h,f,d] * w_proj[h*64+d][j] ----------------
__global__ __launch_bounds__(256) void w2_kernel(const float* __restrict__ kv,
                                                 const float* __restrict__ w_proj,
                                                 bf16_t* __restrict__ W2T) {
  const int bh = blockIdx.x, b = bh >> 3, h = bh & 7;
  const int j0 = blockIdx.y * 64;
  const int t = threadIdx.x;
  __shared__ float kvs[64][64];
  __shared__ float wps[64][64];
  const float* kvp = kv + (size_t)bh * 4096;
  #pragma unroll
  for (int i = 0; i < 16; ++i) ((float*)kvs)[t + 256 * i] = kvp[t + 256 * i];
  {
    const int d = t >> 2, c16 = (t & 3) * 16;
    const float* src = w_proj + (size_t)(h * 64 + d) * 512 + j0 + c16;
    #pragma unroll
    for (int j = 0; j < 16; ++j) wps[d][c16 + j] = src[j];
  }
  __syncthreads();
  const int fq = t >> 4, jq = t & 15;
  float acc[4][4] = {};
  for (int d = 0; d < 64; ++d) {
    float kf[4], wj[4];
    #pragma unroll
    for (int i = 0; i < 4; ++i) kf[i] = kvs[fq * 4 + i][d];
    #pragma unroll
    for (int i = 0; i < 4; ++i) wj[i] = wps[d][jq * 4 + i];
    #pragma unroll
    for (int i = 0; i < 4; ++i)
      #pragma unroll
      for (int j = 0; j < 4; ++j) acc[i][j] += kf[i] * wj[j];
  }
  #pragma unroll
  for (int j = 0; j < 4; ++j)
    #pragma unroll
    for (int i = 0; i < 4; ++i)
      W2T[((size_t)b * 512 + j0 + jq * 4 + j) * 512 + h * 64 + fq * 4 + i] = (bf16_t)acc[i][j];
}

// ---------------- zq[row][h*64+f] = qphi * (1 / sum_f qphi*ksum) ----------------
__global__ __launch_bounds__(256) void zq_kernel(const bf16_t* __restrict__ qphi,
                                                 const float* __restrict__ ksum,
                                                 bf16_t* __restrict__ zq) {
  const int row = blockIdx.x * 4 + (threadIdx.x >> 6);
  const int l = threadIdx.x & 63;
  const int b = row >> 12;
  const int h = l >> 3, f8 = (l & 7) * 8;
  const bf16_t* src = qphi + (size_t)row * 512 + h * 64 + f8;
  bf16x8 v = *(const bf16x8*)src;
  const float* ks = ksum + ((size_t)b * 8 + h) * 64 + f8;
  float part = 0.f;
  float vf[8];
  #pragma unroll
  for (int j = 0; j < 8; ++j) { vf[j] = (float)v[j]; part += vf[j] * ks[j]; }
  part += __shfl_xor(part, 1);
  part += __shfl_xor(part, 2);
  part += __shfl_xor(part, 4);
  const float z = 1.f / part;
  bf16x8 o;
  #pragma unroll
  for (int j = 0; j < 8; ++j) o[j] = (bf16_t)(vf[j] * z);
  *(bf16x8*)(zq + (size_t)row * 512 + h * 64 + f8) = o;
}

extern "C" void kernel_launch(void* const* d_in, const int* in_sizes, int n_in,
                              void* d_out, int out_size, void* d_ws, size_t ws_size,
                              hipStream_t stream) {
  const float* x      = (const float*)d_in[0];
  const float* w_qkv  = (const float*)d_in[1];
  const float* proj   = (const float*)d_in[2];
  const float* w_proj = (const float*)d_in[3];
  const float* b_proj = (const float*)d_in[4];
  float* out = (float*)d_out;
  char* ws = (char*)d_ws;

  // workspace layout (bytes)
  bf16_t* x_bf  = (bf16_t*)(ws + 0);           // 32768*512*2  = 33,554,432
  bf16_t* WeffT = (bf16_t*)(ws + 33554432);    // 1536*512*2   =  1,572,864
  bf16_t* q_phi = (bf16_t*)(ws + 35127296);    // 32768*512*2  = 33,554,432
  bf16_t* kT    = (bf16_t*)(ws + 68681728);    // 64*64*4096*2 = 33,554,432
  bf16_t* vT    = (bf16_t*)(ws + 102236160);   // 64*64*4096*2 = 33,554,432
  float*  kv    = (float*)(ws + 135790592);    // 64*64*64*4   =  1,048,576
  float*  ksum  = (float*)(ws + 136839168);    // 64*64*4      =     16,384
  bf16_t* W2T   = (bf16_t*)(ws + 136855552);   // 8*512*512*2  =  4,194,304
  bf16_t* zq    = (bf16_t*)(ws + 141049856);   // 32768*512*2  = 33,554,432
                                               // total 174,604,288

  prep_qk<<<dim3(16, 8), 256, 0, stream>>>(w_qkv, proj, WeffT);
  prep_v<<<dim3(16, 16), 256, 0, stream>>>(w_qkv, WeffT);
  cast_x<<<16384, 256, 0, stream>>>((const f32x4*)x, (bf16x4*)x_bf, 4194304);
  // q: P=WeffT[0:512] (f rows), Q=x (tokens)
  gemm_pq<0><<<dim3(4, 256, 1), 256, 0, stream>>>(WeffT, x_bf, q_phi, nullptr, nullptr,
                                                  nullptr, nullptr, 0, 0);
  // k,v: P=x (tokens), Q=WeffT[512:1536] (feats)
  gemm_pq<1><<<dim3(256, 8, 1), 256, 0, stream>>>(x_bf, WeffT + 512 * 512, nullptr, kT, vT,
                                                  nullptr, nullptr, 0, 0);
  hipMemsetAsync(kv, 0, 1048576 + 16384, stream);
  kv_mfma<<<dim3(64, 8), 256, 0, stream>>>(kT, vT, kv, ksum);
  w2_kernel<<<dim3(64, 8), 256, 0, stream>>>(kv, w_proj, W2T);
  zq_kernel<<<8192, 256, 0, stream>>>(q_phi, ksum, zq);
  // out: P=W2T[z] (j rows), Q=zq[z] (tokens)
  gemm_pq<2><<<dim3(4, 32, 8), 256, 0, stream>>>(W2T, zq, nullptr, nullptr, nullptr, out,
                                                 b_proj, (size_t)512 * 512,
                                                 (size_t)4096 * 512);
}

// Round 4
// 184.161 us; speedup vs baseline: 1.4656x; 1.0868x over previous
//
#include <hip/hip_runtime.h>
#include <hip/hip_bf16.h>

typedef __bf16 bf16_t;
typedef __bf16 bf16x4 __attribute__((ext_vector_type(4)));
typedef __bf16 bf16x8 __attribute__((ext_vector_type(8)));
typedef float f32x4 __attribute__((ext_vector_type(4)));

__device__ __forceinline__ void gload16(const void* g, void* l) {
  __builtin_amdgcn_global_load_lds((const __attribute__((address_space(1))) void*)g,
                                   (__attribute__((address_space(3))) void*)l, 16, 0, 0);
}

// ---------------- prep: fold proj into w_qkv (q,k halves) ----------------
__global__ __launch_bounds__(256) void prep_qk(const float* __restrict__ w_qkv,
                                               const float* __restrict__ proj,
                                               bf16_t* __restrict__ WeffT) {
  const int half = blockIdx.x >> 3, h = blockIdx.x & 7;
  const int i0 = blockIdx.y * 64;
  __shared__ float P[64 * 64];   // [d][f] == proj[h] layout
  __shared__ float Wt[64][65];   // [ii][d], padded
  const int t = threadIdx.x;
  #pragma unroll
  for (int r = 0; r < 16; ++r) P[t + 256 * r] = proj[(size_t)h * 4096 + t + 256 * r];
  #pragma unroll
  for (int r = 0; r < 16; ++r) {
    const int idx = t + 256 * r;
    Wt[idx >> 6][idx & 63] =
        w_qkv[(size_t)(i0 + (idx >> 6)) * 1536 + half * 512 + h * 64 + (idx & 63)];
  }
  __syncthreads();
  const int i = t & 63, fg = t >> 6;
  for (int f = fg; f < 64; f += 4) {
    float s = 0.f;
    #pragma unroll
    for (int d = 0; d < 64; ++d) s += Wt[i][d] * P[d * 64 + f];
    WeffT[(size_t)(half * 512 + h * 64 + f) * 512 + i0 + i] = (bf16_t)s;
  }
}

// ---------------- prep: v passthrough transpose ----------------
__global__ __launch_bounds__(256) void prep_v(const float* __restrict__ w_qkv,
                                              bf16_t* __restrict__ WeffT) {
  __shared__ bf16_t tile[32][33];
  const int i0 = blockIdx.x * 32, n0 = blockIdx.y * 32;
  const int tn = threadIdx.x & 31, ti = threadIdx.x >> 5;
  #pragma unroll
  for (int p = 0; p < 4; ++p) {
    const int i = ti + p * 8;
    tile[i][tn] = (bf16_t)w_qkv[(size_t)(i0 + i) * 1536 + 1024 + n0 + tn];
  }
  __syncthreads();
  #pragma unroll
  for (int p = 0; p < 4; ++p) {
    const int n = ti + p * 8;
    WeffT[(size_t)(1024 + n0 + n) * 512 + i0 + tn] = tile[tn][n];
  }
}

// ---------------- cast x (f32) -> bf16 ----------------
__global__ __launch_bounds__(256) void cast_x(const f32x4* __restrict__ x,
                                              bf16x4* __restrict__ xb, int n4) {
  int i = blockIdx.x * 256 + threadIdx.x;
  if (i < n4) {
    f32x4 v = x[i];
    bf16x4 o;
    #pragma unroll
    for (int j = 0; j < 4; ++j) o[j] = (bf16_t)v[j];
    xb[i] = o;
  }
}

// ==================== merged QKV GEMM ====================
// 3072 blocks 1-D, XCD-chunk swizzled. bid -> (tok_blk = bid/12, cb = bid%12).
// cb<4:  q path. P=WeffT rows [cb*128,+128) (feats), Q=x tokens. out q_phi[token][feat].
// cb>=4: kv path. P=x tokens, Q=WeffT rows [512+(cb-4)*128). out kT/vT[feat][token].
// Double-buffered LDS (64 KB), 1 barrier/K-step; LDS-restaged coalesced epilogue.
__global__ __launch_bounds__(256) void gemm_qkv(const bf16_t* __restrict__ x_bf,
                                                const bf16_t* __restrict__ WeffT,
                                                bf16_t* __restrict__ q_phi,
                                                bf16_t* __restrict__ kT,
                                                bf16_t* __restrict__ vT) {
  constexpr int K = 512, BK = 64;
  __shared__ alignas(16) char smem[65536];  // 2 bufs x (P 16K + Q 16K)
  const int t = threadIdx.x, w = t >> 6, l = t & 63;
  const int hw = blockIdx.x;
  const int bid = (hw & 7) * 384 + (hw >> 3);   // XCD-chunked (3072/8=384)
  const int tok_blk = bid / 12, cb = bid % 12;
  const size_t tok0 = (size_t)tok_blk * 128;
  const bool qpath = (cb < 4);
  const bf16_t* Pp = qpath ? (WeffT + (size_t)cb * 128 * 512) : (x_bf + tok0 * 512);
  const bf16_t* Qp = qpath ? (x_bf + tok0 * 512)
                           : (WeffT + (size_t)(512 + (cb - 4) * 128) * 512);

  const int wr = w >> 1, wc = w & 1;
  const int lrow = l & 15, lkb = l >> 4;
  const int st_r = l >> 3;
  const int st_c = ((l & 7) ^ st_r) * 8;  // pre-swizzled source col (bf16 units)
  size_t p_src[4], q_src[4];
  #pragma unroll
  for (int c = 0; c < 4; ++c) {
    const int q8 = c * 4 + w;
    p_src[c] = (size_t)(q8 * 8 + st_r) * K + st_c;
    q_src[c] = (size_t)(q8 * 8 + st_r) * K + st_c;
  }

  f32x4 acc[4][4];
  #pragma unroll
  for (int m = 0; m < 4; ++m)
    #pragma unroll
    for (int n = 0; n < 4; ++n) acc[m][n] = f32x4{0.f, 0.f, 0.f, 0.f};

  // prologue: stage tile 0 into buf 0
  #pragma unroll
  for (int c = 0; c < 4; ++c) {
    const int q8 = c * 4 + w;
    gload16(Pp + p_src[c], smem + q8 * 1024);
    gload16(Qp + q_src[c], smem + 16384 + q8 * 1024);
  }
  __syncthreads();

  int cur = 0;
  for (int kt = 0; kt < K; kt += BK) {
    if (kt + BK < K) {  // prefetch next tile into other buffer
      char* nb = smem + (cur ^ 1) * 32768;
      #pragma unroll
      for (int c = 0; c < 4; ++c) {
        const int q8 = c * 4 + w;
        gload16(Pp + p_src[c] + kt + BK, nb + q8 * 1024);
        gload16(Qp + q_src[c] + kt + BK, nb + 16384 + q8 * 1024);
      }
    }
    const char* PsB = smem + cur * 32768;
    const char* QsB = PsB + 16384;
    bf16x8 pf[4][2], qf[4][2];
    #pragma unroll
    for (int m = 0; m < 4; ++m) {
      const int r = wr * 64 + m * 16 + lrow;
      #pragma unroll
      for (int kk = 0; kk < 2; ++kk) {
        const int kb = lkb + kk * 4;
        pf[m][kk] = *(const bf16x8*)(PsB + r * 128 + (((kb ^ (r & 7)) & 7) << 4));
      }
    }
    #pragma unroll
    for (int n = 0; n < 4; ++n) {
      const int r = wc * 64 + n * 16 + lrow;
      #pragma unroll
      for (int kk = 0; kk < 2; ++kk) {
        const int kb = lkb + kk * 4;
        qf[n][kk] = *(const bf16x8*)(QsB + r * 128 + (((kb ^ (r & 7)) & 7) << 4));
      }
    }
    #pragma unroll
    for (int m = 0; m < 4; ++m)
      #pragma unroll
      for (int n = 0; n < 4; ++n) {
        acc[m][n] = __builtin_amdgcn_mfma_f32_16x16x32_bf16(pf[m][0], qf[n][0], acc[m][n], 0, 0, 0);
        acc[m][n] = __builtin_amdgcn_mfma_f32_16x16x32_bf16(pf[m][1], qf[n][1], acc[m][n], 0, 0, 0);
      }
    __syncthreads();  // readers done with cur; prefetch into cur^1 landed
    cur ^= 1;
  }

  // ---- epilogue: restage tile [128 qrows][128 prows] bf16 in LDS, coalesced store ----
  bf16_t* ep = (bf16_t*)smem;  // 32 KB, rows 256 B, 16-B-unit XOR swizzle
  const bool doElu = qpath || (cb < 8);  // q and k get elu+1; v passthrough
  #pragma unroll
  for (int n = 0; n < 4; ++n) {
    const int qc = wc * 64 + n * 16 + lrow;
    #pragma unroll
    for (int m = 0; m < 4; ++m) {
      const int pr0 = wr * 64 + m * 16 + lkb * 4;
      bf16x4 o;
      #pragma unroll
      for (int j = 0; j < 4; ++j) {
        float v = acc[m][n][j];
        if (doElu) v = v > 0.f ? v + 1.f : __expf(v);
        o[j] = (bf16_t)v;
      }
      const int u = pr0 >> 3;
      *(bf16x4*)((char*)ep + qc * 256 + ((u ^ (qc & 15)) << 4) + (pr0 & 7) * 2) = o;
    }
  }
  __syncthreads();
  #pragma unroll
  for (int i = 0; i < 8; ++i) {
    const int flat = i * 256 + t;
    const int qc2 = flat >> 4, u2 = flat & 15;
    bf16x8 vv = *(const bf16x8*)((char*)ep + qc2 * 256 + ((u2 ^ (qc2 & 15)) << 4));
    if (qpath) {
      *(bf16x8*)&q_phi[(tok0 + qc2) * 512 + cb * 128 + u2 * 8] = vv;
    } else {
      const int f512 = (cb - 4) * 128 + qc2;  // 0..1023: k then v
      bf16_t* dst = (f512 < 512 ? kT + ((size_t)(tok0 >> 12) * 512 + f512) * 4096
                                : vT + ((size_t)(tok0 >> 12) * 512 + (f512 - 512)) * 4096) +
                    (tok0 & 4095) + u2 * 8;
      *(bf16x8*)dst = vv;
    }
  }
}

// ---------------- kv[f][d] = sum_n kT[f][n]*vT[d][n]; ksum[f] = sum_n kT[f][n] ----
__global__ __launch_bounds__(256) void kv_mfma(const bf16_t* __restrict__ kT,
                                               const bf16_t* __restrict__ vT,
                                               float* __restrict__ kv,
                                               float* __restrict__ ksum) {
  const int bh = blockIdx.x;
  const int nbase = blockIdx.y * 512;
  __shared__ alignas(16) char smem[32768];  // 2 bufs x (K 8K + V 8K)
  const int t = threadIdx.x, w = t >> 6, l = t & 63;
  const int wr = w >> 1, wc = w & 1;
  const int lrow = l & 15, lkb = l >> 4;
  const int st_r = l >> 3;
  const int st_c = ((l & 7) ^ st_r) * 8;
  const bf16_t* Kp = kT + (size_t)bh * 64 * 4096;
  const bf16_t* Vp = vT + (size_t)bh * 64 * 4096;

  f32x4 acc[2][2];
  #pragma unroll
  for (int m = 0; m < 2; ++m)
    #pragma unroll
    for (int n = 0; n < 2; ++n) acc[m][n] = f32x4{0.f, 0.f, 0.f, 0.f};
  float ksf[2] = {0.f, 0.f};

  #pragma unroll
  for (int c = 0; c < 2; ++c) {
    const int q8 = w * 2 + c;
    gload16(Kp + (size_t)(q8 * 8 + st_r) * 4096 + nbase + st_c, smem + q8 * 1024);
    gload16(Vp + (size_t)(q8 * 8 + st_r) * 4096 + nbase + st_c, smem + 8192 + q8 * 1024);
  }
  __syncthreads();

  int cur = 0;
  for (int st = 0; st < 8; ++st) {
    if (st < 7) {
      char* nb = smem + (cur ^ 1) * 16384;
      const int nb2 = nbase + (st + 1) * 64;
      #pragma unroll
      for (int c = 0; c < 2; ++c) {
        const int q8 = w * 2 + c;
        gload16(Kp + (size_t)(q8 * 8 + st_r) * 4096 + nb2 + st_c, nb + q8 * 1024);
        gload16(Vp + (size_t)(q8 * 8 + st_r) * 4096 + nb2 + st_c, nb + 8192 + q8 * 1024);
      }
    }
    const char* KsB = smem + cur * 16384;
    const char* VsB = KsB + 8192;
    bf16x8 af[2][2], bf[2][2];
    #pragma unroll
    for (int m = 0; m < 2; ++m) {
      const int r = wr * 32 + m * 16 + lrow;
      #pragma unroll
      for (int kk = 0; kk < 2; ++kk) {
        const int kb = lkb + kk * 4;
        af[m][kk] = *(const bf16x8*)(KsB + r * 128 + (((kb ^ (r & 7)) & 7) << 4));
      }
    }
    #pragma unroll
    for (int n = 0; n < 2; ++n) {
      const int r = wc * 32 + n * 16 + lrow;
      #pragma unroll
      for (int kk = 0; kk < 2; ++kk) {
        const int kb = lkb + kk * 4;
        bf[n][kk] = *(const bf16x8*)(VsB + r * 128 + (((kb ^ (r & 7)) & 7) << 4));
      }
    }
    #pragma unroll
    for (int m = 0; m < 2; ++m)
      #pragma unroll
      for (int n = 0; n < 2; ++n) {
        acc[m][n] = __builtin_amdgcn_mfma_f32_16x16x32_bf16(af[m][0], bf[n][0], acc[m][n], 0, 0, 0);
        acc[m][n] = __builtin_amdgcn_mfma_f32_16x16x32_bf16(af[m][1], bf[n][1], acc[m][n], 0, 0, 0);
      }
    if (wc == 0) {
      #pragma unroll
      for (int m = 0; m < 2; ++m)
        #pragma unroll
        for (int kk = 0; kk < 2; ++kk)
          #pragma unroll
          for (int j = 0; j < 8; ++j) ksf[m] += (float)af[m][kk][j];
    }
    __syncthreads();
    cur ^= 1;
  }

  float* kvp = kv + (size_t)bh * 4096;
  #pragma unroll
  for (int m = 0; m < 2; ++m)
    #pragma unroll
    for (int n = 0; n < 2; ++n)
      #pragma unroll
      for (int j = 0; j < 4; ++j)
        atomicAdd(&kvp[(wr * 32 + m * 16 + lkb * 4 + j) * 64 + wc * 32 + n * 16 + lrow],
                  acc[m][n][j]);
  if (wc == 0) {
    #pragma unroll
    for (int m = 0; m < 2; ++m) {
      float s = ksf[m];
      s += __shfl_xor(s, 16);
      s += __shfl_xor(s, 32);
      if (l < 16) atomicAdd(&ksum[(size_t)bh * 64 + wr * 32 + m * 16 + l], s);
    }
  }
}

// ---------------- W2T[b][j][h*64+f] = sum_d kv[b,h,f,d] * w_proj[h*64+d][j] ----------------
__global__ __launch_bounds__(256) void w2_kernel(const float* __restrict__ kv,
                                                 const float* __restrict__ w_proj,
                                                 bf16_t* __restrict__ W2T) {
  const int bh = blockIdx.x, b = bh >> 3, h = bh & 7;
  const int j0 = blockIdx.y * 64;
  const int t = threadIdx.x;
  __shared__ float kvs[64][64];
  __shared__ float wps[64][64];
  const float* kvp = kv + (size_t)bh * 4096;
  #pragma unroll
  for (int i = 0; i < 16; ++i) ((float*)kvs)[t + 256 * i] = kvp[t + 256 * i];
  {
    const int d = t >> 2, c16 = (t & 3) * 16;
    const float* src = w_proj + (size_t)(h * 64 + d) * 512 + j0 + c16;
    #pragma unroll
    for (int j = 0; j < 16; ++j) wps[d][c16 + j] = src[j];
  }
  __syncthreads();
  const int fq = t >> 4, jq = t & 15;
  float acc[4][4] = {};
  for (int d = 0; d < 64; ++d) {
    float kf[4], wj[4];
    #pragma unroll
    for (int i = 0; i < 4; ++i) kf[i] = kvs[fq * 4 + i][d];
    #pragma unroll
    for (int i = 0; i < 4; ++i) wj[i] = wps[d][jq * 4 + i];
    #pragma unroll
    for (int i = 0; i < 4; ++i)
      #pragma unroll
      for (int j = 0; j < 4; ++j) acc[i][j] += kf[i] * wj[j];
  }
  #pragma unroll
  for (int j = 0; j < 4; ++j)
    #pragma unroll
    for (int i = 0; i < 4; ++i)
      W2T[((size_t)b * 512 + j0 + jq * 4 + j) * 512 + h * 64 + fq * 4 + i] = (bf16_t)acc[i][j];
}

// ---------------- zq[row][h*64+f] = qphi * (1 / sum_f qphi*ksum) (per head) ----------------
__global__ __launch_bounds__(256) void zq_kernel(const bf16_t* __restrict__ qphi,
                                                 const float* __restrict__ ksum,
                                                 bf16_t* __restrict__ zq) {
  const int row = blockIdx.x * 4 + (threadIdx.x >> 6);
  const int l = threadIdx.x & 63;
  const int b = row >> 12;
  const int h = l >> 3, f8 = (l & 7) * 8;
  const bf16_t* src = qphi + (size_t)row * 512 + h * 64 + f8;
  bf16x8 v = *(const bf16x8*)src;
  const float* ks = ksum + ((size_t)b * 8 + h) * 64 + f8;
  float part = 0.f;
  float vf[8];
  #pragma unroll
  for (int j = 0; j < 8; ++j) { vf[j] = (float)v[j]; part += vf[j] * ks[j]; }
  part += __shfl_xor(part, 1);
  part += __shfl_xor(part, 2);
  part += __shfl_xor(part, 4);
  const float z = 1.f / part;
  bf16x8 o;
  #pragma unroll
  for (int j = 0; j < 8; ++j) o[j] = (bf16_t)(vf[j] * z);
  *(bf16x8*)(zq + (size_t)row * 512 + h * 64 + f8) = o;
}

// ==================== output GEMM: out[z][token][j] = zq . W2T^T + bias ====================
// 1024 blocks 1-D, XCD-chunk swizzled. P=W2T[z] (j rows), Q=zq[z] (tokens).
__global__ __launch_bounds__(256) void gemm_out(const bf16_t* __restrict__ W2T,
                                                const bf16_t* __restrict__ zq,
                                                float* __restrict__ Cout,
                                                const float* __restrict__ bias) {
  constexpr int K = 512, BK = 64;
  __shared__ alignas(16) char smem[65536];
  const int t = threadIdx.x, w = t >> 6, l = t & 63;
  const int hw = blockIdx.x;
  const int bid = (hw & 7) * 128 + (hw >> 3);   // 1024/8=128
  const int z = bid >> 7;
  const int rem = bid & 127;
  const int qblk = rem >> 2, pblk = rem & 3;
  const size_t tok0 = (size_t)qblk * 128;
  const int pj0 = pblk * 128;
  const bf16_t* Pp = W2T + ((size_t)z * 512 + pj0) * 512;
  const bf16_t* Qp = zq + ((size_t)z * 4096 + tok0) * 512;

  const int wr = w >> 1, wc = w & 1;
  const int lrow = l & 15, lkb = l >> 4;
  const int st_r = l >> 3;
  const int st_c = ((l & 7) ^ st_r) * 8;

  f32x4 acc[4][4];
  #pragma unroll
  for (int m = 0; m < 4; ++m)
    #pragma unroll
    for (int n = 0; n < 4; ++n) acc[m][n] = f32x4{0.f, 0.f, 0.f, 0.f};

  #pragma unroll
  for (int c = 0; c < 4; ++c) {
    const int q8 = c * 4 + w;
    gload16(Pp + (size_t)(q8 * 8 + st_r) * K + st_c, smem + q8 * 1024);
    gload16(Qp + (size_t)(q8 * 8 + st_r) * K + st_c, smem + 16384 + q8 * 1024);
  }
  __syncthreads();

  int cur = 0;
  for (int kt = 0; kt < K; kt += BK) {
    if (kt + BK < K) {
      char* nb = smem + (cur ^ 1) * 32768;
      #pragma unroll
      for (int c = 0; c < 4; ++c) {
        const int q8 = c * 4 + w;
        gload16(Pp + (size_t)(q8 * 8 + st_r) * K + kt + BK + st_c, nb + q8 * 1024);
        gload16(Qp + (size_t)(q8 * 8 + st_r) * K + kt + BK + st_c, nb + 16384 + q8 * 1024);
      }
    }
    const char* PsB = smem + cur * 32768;
    const char* QsB = PsB + 16384;
    bf16x8 pf[4][2], qf[4][2];
    #pragma unroll
    for (int m = 0; m < 4; ++m) {
      const int r = wr * 64 + m * 16 + lrow;
      #pragma unroll
      for (int kk = 0; kk < 2; ++kk) {
        const int kb = lkb + kk * 4;
        pf[m][kk] = *(const bf16x8*)(PsB + r * 128 + (((kb ^ (r & 7)) & 7) << 4));
      }
    }
    #pragma unroll
    for (int n = 0; n < 4; ++n) {
      const int r = wc * 64 + n * 16 + lrow;
      #pragma unroll
      for (int kk = 0; kk < 2; ++kk) {
        const int kb = lkb + kk * 4;
        qf[n][kk] = *(const bf16x8*)(QsB + r * 128 + (((kb ^ (r & 7)) & 7) << 4));
      }
    }
    #pragma unroll
    for (int m = 0; m < 4; ++m)
      #pragma unroll
      for (int n = 0; n < 4; ++n) {
        acc[m][n] = __builtin_amdgcn_mfma_f32_16x16x32_bf16(pf[m][0], qf[n][0], acc[m][n], 0, 0, 0);
        acc[m][n] = __builtin_amdgcn_mfma_f32_16x16x32_bf16(pf[m][1], qf[n][1], acc[m][n], 0, 0, 0);
      }
    __syncthreads();
    cur ^= 1;
  }

  // ---- epilogue: two phases of [64 token-rows][128 j] f32 (32 KB each) ----
  float* ep = (float*)smem;  // rows 512 B = 32 x 16B units, XOR swizzle
  #pragma unroll
  for (int p = 0; p < 2; ++p) {
    if (p) __syncthreads();  // phase 0 entered right after k-loop's final barrier
    #pragma unroll
    for (int nn2 = 0; nn2 < 2; ++nn2) {
      const int n = p * 2 + nn2;
      const int r6 = wc * 32 + (n & 1) * 16 + lrow;  // compressed row
      #pragma unroll
      for (int m = 0; m < 4; ++m) {
        const int pr0 = wr * 64 + m * 16 + lkb * 4;
        f32x4 v = acc[m][n];
        const f32x4 bv = *(const f32x4*)&bias[pj0 + pr0];
        #pragma unroll
        for (int j = 0; j < 4; ++j) v[j] += bv[j];
        const int u = pr0 >> 2;  // 0..31
        *(f32x4*)((char*)ep + r6 * 512 + ((u ^ (r6 & 31)) << 4)) = v;
      }
    }
    __syncthreads();
    #pragma unroll
    for (int i = 0; i < 8; ++i) {
      const int flat = i * 256 + t;
      const int r6 = flat >> 5, u2 = flat & 31;
      f32x4 v = *(const f32x4*)((char*)ep + r6 * 512 + ((u2 ^ (r6 & 31)) << 4));
      const int qc = (r6 >> 5) * 64 + p * 32 + (r6 & 31);
      *(f32x4*)&Cout[((size_t)z * 4096 + tok0 + qc) * 512 + pj0 + u2 * 4] = v;
    }
  }
}

extern "C" void kernel_launch(void* const* d_in, const int* in_sizes, int n_in,
                              void* d_out, int out_size, void* d_ws, size_t ws_size,
                              hipStream_t stream) {
  const float* x      = (const float*)d_in[0];
  const float* w_qkv  = (const float*)d_in[1];
  const float* proj   = (const float*)d_in[2];
  const float* w_proj = (const float*)d_in[3];
  const float* b_proj = (const float*)d_in[4];
  float* out = (float*)d_out;
  char* ws = (char*)d_ws;

  // workspace layout (bytes)
  bf16_t* x_bf  = (bf16_t*)(ws + 0);           // 32768*512*2  = 33,554,432
  bf16_t* WeffT = (bf16_t*)(ws + 33554432);    // 1536*512*2   =  1,572,864
  bf16_t* q_phi = (bf16_t*)(ws + 35127296);    // 32768*512*2  = 33,554,432
  bf16_t* kT    = (bf16_t*)(ws + 68681728);    // 64*64*4096*2 = 33,554,432
  bf16_t* vT    = (bf16_t*)(ws + 102236160);   // 64*64*4096*2 = 33,554,432
  float*  kv    = (float*)(ws + 135790592);    // 64*64*64*4   =  1,048,576
  float*  ksum  = (float*)(ws + 136839168);    // 64*64*4      =     16,384
  bf16_t* W2T   = (bf16_t*)(ws + 136855552);   // 8*512*512*2  =  4,194,304
  bf16_t* zq    = (bf16_t*)(ws + 141049856);   // 32768*512*2  = 33,554,432

  prep_qk<<<dim3(16, 8), 256, 0, stream>>>(w_qkv, proj, WeffT);
  prep_v<<<dim3(16, 16), 256, 0, stream>>>(w_qkv, WeffT);
  cast_x<<<16384, 256, 0, stream>>>((const f32x4*)x, (bf16x4*)x_bf, 4194304);
  gemm_qkv<<<3072, 256, 0, stream>>>(x_bf, WeffT, q_phi, kT, vT);
  hipMemsetAsync(kv, 0, 1048576 + 16384, stream);
  kv_mfma<<<dim3(64, 8), 256, 0, stream>>>(kT, vT, kv, ksum);
  w2_kernel<<<dim3(64, 8), 256, 0, stream>>>(kv, w_proj, W2T);
  zq_kernel<<<8192, 256, 0, stream>>>(q_phi, ksum, zq);
  gemm_out<<<1024, 256, 0, stream>>>(W2T, zq, out, b_proj);
}